// Round 11
// baseline (179.174 us; speedup 1.0000x reference)
//
#include <hip/hip_runtime.h>
#include <hip/hip_bf16.h>
#include <cmath>

#define NTOK 32768
#define HDIM 512
#define GVDIM 640
#define VDIM 320
#define DG 128
#define OUT0_SIZE (NTOK * 256)
// bf16-MFMA logit error bound: per-term 2^-9 rel, K=512 random-signed ->
// e_max ~ 0.003.  Margin >= 2*e_max needed; 0.010 keeps 1.7x headroom.
#define MARGIN 0.010f

typedef __attribute__((ext_vector_type(8))) short s16x8;
typedef __attribute__((ext_vector_type(8))) unsigned short u16x8;
typedef __attribute__((ext_vector_type(4))) float f32x4;

__device__ __forceinline__ unsigned short f2bf(float f) {
    unsigned u = __float_as_uint(f);
    return (unsigned short)((u + 0x7FFFu + ((u >> 16) & 1u)) >> 16);  // RTNE
}

// 8x fp32 -> 8x bf16 via HW v_cvt_pk_bf16_f32 (RTNE, bit-identical to f2bf)
__device__ __forceinline__ u16x8 cvt8(const float4 a, const float4 b) {
    union { __hip_bfloat162 h[4]; u16x8 v; } u;
    u.h[0] = __float22bfloat162_rn(float2{a.x, a.y});
    u.h[1] = __float22bfloat162_rn(float2{a.z, a.w});
    u.h[2] = __float22bfloat162_rn(float2{b.x, b.y});
    u.h[3] = __float22bfloat162_rn(float2{b.z, b.w});
    return u.v;
}

// ---- prep: W [512][640] fp32 -> Wt bf16 [640][512] + Wt32 fp32 [640][512] ----
__global__ __launch_bounds__(256) void k_prep(const float* __restrict__ W,
                                              unsigned short* __restrict__ Wt,
                                              float* __restrict__ Wt32,
                                              int* __restrict__ hist) {
    int n = blockIdx.x;
    if (threadIdx.x == 0) hist[n] = 0;
#pragma unroll
    for (int k2 = 0; k2 < 2; ++k2) {
        int k = k2 * 256 + threadIdx.x;
        float w = W[(size_t)k * 640 + n];
        Wt[(size_t)n * 512 + k]   = f2bf(w);
        Wt32[(size_t)n * 512 + k] = w;
    }
}

// ---- MFMA GEMM (round-4 proven): fp32 A converted in-staging via cvt_pk ----
__global__ __launch_bounds__(256) void k_gemm(
    const float* __restrict__ A32,          // [NTOK][512] fp32 (hs, raw input)
    const unsigned short* __restrict__ Bt,  // [640][512] bf16
    const float* __restrict__ bias,
    uint4* __restrict__ meta)               // [NTOK][10]
{
    __shared__ short As[128 * 64];
    __shared__ short Bs[128 * 64];

    const int tid  = threadIdx.x;
    const int lane = tid & 63;
    const int wid  = __builtin_amdgcn_readfirstlane(tid >> 6);

    // XCD-chunked swizzle, nb fastest (A re-reads are same-XCD L2/L3 hits)
    const int bid = blockIdx.x;                 // 1280 = 8 XCD * 160
    const int g   = (bid & 7) * 160 + (bid >> 3);
    const int mb  = g / 5;                      // 0..255
    const int nb  = g - mb * 5;                 // 0..4
    const int tok0 = mb * 128;
    const int col0 = nb * 128;

    const int r8 = lane >> 3;
    const int c8 = lane & 7;
    const int cl = c8 ^ r8;

    const float*          gA = A32 + (size_t)(tok0 + wid * 32 + r8) * 512 + cl * 8;
    const unsigned short* gB = Bt  + (size_t)(col0 + wid * 32 + r8) * 512 + cl * 8;
    short* wAs = As + (wid * 32 + r8) * 64 + c8 * 8;   // this thread's LDS dest

    const int quad = lane >> 4;
    const int m16  = lane & 15;
    const int wm   = (wid >> 1) * 64;
    const int wn   = (wid & 1) * 64;

    f32x4 acc[4][4];
#pragma unroll
    for (int mt = 0; mt < 4; ++mt)
#pragma unroll
        for (int nt = 0; nt < 4; ++nt) acc[mt][nt] = (f32x4){0.f, 0.f, 0.f, 0.f};

    for (int kb = 0; kb < 8; ++kb) {
        // B: async DMA into LDS (issues first; flies under the A staging work)
#pragma unroll
        for (int i = 0; i < 4; ++i) {
            __builtin_amdgcn_global_load_lds(
                (__attribute__((address_space(1))) void*)(gB + (size_t)i * 8 * 512 + kb * 64),
                (__attribute__((address_space(3))) void*)(Bs + (wid * 32 + i * 8) * 64),
                16, 0, 0);
        }
        // A: fp32 load -> HW cvt_pk bf16 -> ds_write (swizzled layout)
#pragma unroll
        for (int i = 0; i < 4; ++i) {
            const float* pa = gA + (size_t)i * 8 * 512 + kb * 64;
            float4 a0 = *(const float4*)pa;
            float4 a1 = *(const float4*)(pa + 4);
            *(u16x8*)(wAs + i * 8 * 64) = cvt8(a0, a1);
        }
        __syncthreads();
#pragma unroll
        for (int ks = 0; ks < 2; ++ks) {
            s16x8 af[4], bf[4];
            const int kch = ks * 4 + quad;
#pragma unroll
            for (int t = 0; t < 4; ++t) {
                int arow = wm + t * 16 + m16;
                af[t] = *(const s16x8*)(As + arow * 64 + (kch ^ (arow & 7)) * 8);
                int brow = wn + t * 16 + m16;
                bf[t] = *(const s16x8*)(Bs + brow * 64 + (kch ^ (brow & 7)) * 8);
            }
#pragma unroll
            for (int mt = 0; mt < 4; ++mt)
#pragma unroll
                for (int nt = 0; nt < 4; ++nt)
                    acc[mt][nt] = __builtin_amdgcn_mfma_f32_16x16x32_bf16(
                        af[mt], bf[nt], acc[mt][nt], 0, 0, 0);
        }
        __syncthreads();
    }

    float bv[4];
#pragma unroll
    for (int nt = 0; nt < 4; ++nt) bv[nt] = bias[col0 + wn + nt * 16 + m16];

    // ---- fused reduction epilogue: this wave owns chunk ch (64 cols) ----
    const int ch = (col0 + wn) >> 6;          // global chunk 0..9
#pragma unroll
    for (int mt = 0; mt < 4; ++mt) {
#pragma unroll
        for (int r = 0; r < 4; ++r) {
            float v0 = acc[mt][0][r] + bv[0];
            float v1 = acc[mt][1][r] + bv[1];
            float v2 = acc[mt][2][r] + bv[2];
            float v3 = acc[mt][3][r] + bv[3];
            float cmax = fmaxf(fmaxf(v0, v1), fmaxf(v2, v3));
#pragma unroll
            for (int off = 1; off <= 8; off <<= 1)
                cmax = fmaxf(cmax, __shfl_xor(cmax, off));   // over m16 lanes
            const float t = cmax - MARGIN;
            unsigned long long b0 = __ballot(v0 >= t);
            unsigned long long b1 = __ballot(v1 >= t);
            unsigned long long b2 = __ballot(v2 >= t);
            unsigned long long b3 = __ballot(v3 >= t);
            if (m16 == 0) {
                unsigned q16 = quad * 16;
                unsigned long long mask =
                      (((b0 >> q16) & 0xFFFFull))
                    | (((b1 >> q16) & 0xFFFFull) << 16)
                    | (((b2 >> q16) & 0xFFFFull) << 32)
                    | (((b3 >> q16) & 0xFFFFull) << 48);
                int token = tok0 + wm + mt * 16 + quad * 4 + r;
                uint4 e;
                e.x = __float_as_uint(cmax);
                e.y = (unsigned)(mask & 0xFFFFFFFFull);
                e.z = (unsigned)(mask >> 32);
                e.w = 0;
                meta[(size_t)token * 10 + ch] = e;
            }
        }
    }
}

// ---- fused decide + rescore: block owns 256 token-groups ----
// Phase 1: per-thread decide (identical numerics to r4 k_decide); ambiguous
// items go to a per-block LDS list (no global ctr/list round-trip).
// Phase 2: the block's 4 waves drain the list with the r4 wave-parallel
// exact-fp32 rescore.  Gather stays a separate massively-parallel launch.
__global__ __launch_bounds__(256) void k_dr(
    const uint4* __restrict__ meta, const float* __restrict__ hs,
    const float* __restrict__ Wt32, const float* __restrict__ bias,
    int* __restrict__ idx_out, int* __restrict__ hist)
{
    __shared__ int pend[256];
    __shared__ int pcnt;

    const int tid = threadIdx.x;
    if (tid == 0) pcnt = 0;
    __syncthreads();

    // ---- phase 1: decide ----
    {
        const int tg  = blockIdx.x * 256 + tid;   // 65536 total
        const int tok = tg >> 1;
        const int grp = tg & 1;

        const uint4* mp = meta + (size_t)tok * 10 + grp * 5;
        float pm[5]; unsigned long long mk[5];
#pragma unroll
        for (int j = 0; j < 5; ++j) {
            uint4 e = mp[j];
            pm[j] = __uint_as_float(e.x);
            mk[j] = ((unsigned long long)e.z << 32) | e.y;
        }
        float M = fmaxf(fmaxf(fmaxf(pm[0], pm[1]), fmaxf(pm[2], pm[3])), pm[4]);
        const float thr = M - MARGIN;

        int nq = 0, qc = 0;
#pragma unroll
        for (int j = 0; j < 5; ++j)
            if (pm[j] >= thr) { ++nq; qc = j; }

        if (nq == 1 && __popcll(mk[qc]) == 1) {
            int col = qc * 64 + (__ffsll((long long)mk[qc]) - 1);
            idx_out[tg] = col;
            atomicAdd(&hist[grp * VDIM + col], 1);
        } else {
            int p = atomicAdd(&pcnt, 1);      // LDS atomic
            pend[p] = tid;
        }
    }
    __syncthreads();

    // ---- phase 2: wave-parallel exact rescore of this block's pending ----
    const int lane = tid & 63;
    const int w    = tid >> 6;                // 0..3
    const int np   = pcnt;
    for (int it = w; it < np; it += 4) {
        const int ltid = pend[it];
        const int tg   = blockIdx.x * 256 + ltid;
        const int tok  = tg >> 1;
        const int grp  = tg & 1;

        const uint4* mp = meta + (size_t)tok * 10 + grp * 5;
        float pm[5]; unsigned long long mk[5];
#pragma unroll
        for (int j = 0; j < 5; ++j) {
            uint4 e = mp[j];
            pm[j] = __uint_as_float(e.x);
            mk[j] = ((unsigned long long)e.z << 32) | e.y;
        }
        float M = fmaxf(fmaxf(fmaxf(pm[0], pm[1]), fmaxf(pm[2], pm[3])), pm[4]);
        const float thr = M - MARGIN;

        float hsr[8];
#pragma unroll
        for (int i = 0; i < 8; ++i) hsr[i] = hs[(size_t)tok * 512 + i * 64 + lane];

        float bestv = -INFINITY;
        int   besti = 0;
#pragma unroll
        for (int j = 0; j < 5; ++j) {
            if (pm[j] < thr) continue;
            unsigned long long m = mk[j];
            while (m) {
                int b = __ffsll((long long)m) - 1; m &= m - 1;
                int col  = j * 64 + b;
                int gcol = grp * VDIM + col;
                const float* wrow = Wt32 + (size_t)gcol * 512;
                float p = 0.f;
#pragma unroll
                for (int i = 0; i < 8; ++i)
                    p = fmaf(hsr[i], wrow[i * 64 + lane], p);   // coalesced
#pragma unroll
                for (int off = 32; off >= 1; off >>= 1) p += __shfl_xor(p, off);
                float val = p + bias[gcol];
                if (val > bestv) { bestv = val; besti = col; }  // asc col => first-max
            }
        }
        if (lane == 0) {
            idx_out[tg] = besti;
            atomicAdd(&hist[grp * VDIM + besti], 1);
        }
    }
}

// ---- gather codevectors (all tokens); block 0 also computes perplexity ----
__global__ __launch_bounds__(256) void k_gather(
    const float* __restrict__ cb, const int* __restrict__ idx,
    const int* __restrict__ hist, float* __restrict__ out,
    float* __restrict__ perp)
{
    __shared__ float sh[GVDIM];
    int tid  = threadIdx.x;
    int t    = blockIdx.x * 4 + (tid >> 6);
    int lane = tid & 63;
    int g    = lane >> 5;
    int q    = lane & 31;
    int i    = idx[t * 2 + g];
    const float4* src = (const float4*)(cb + (size_t)(g * VDIM + i) * DG);
    float4 v = src[q];
    ((float4*)(out + (size_t)t * 256))[g * 32 + q] = v;

    if (blockIdx.x == 0) {
        for (int u = tid; u < GVDIM; u += 256) {
            float p = (float)hist[u] * (1.0f / (float)NTOK);
            sh[u] = p * logf(p + 1e-7f);
        }
        __syncthreads();
        if (tid == 0) {
            float s0 = 0.f, s1 = 0.f;
            for (int u = 0; u < VDIM; ++u)  s0 += sh[u];
            for (int u = VDIM; u < GVDIM; ++u) s1 += sh[u];
            perp[0] = expf(-s0) + expf(-s1);
        }
    }
}

extern "C" void kernel_launch(void* const* d_in, const int* in_sizes, int n_in,
                              void* d_out, int out_size, void* d_ws, size_t ws_size,
                              hipStream_t stream)
{
    const float* hs   = (const float*)d_in[0];
    const float* W    = (const float*)d_in[1];
    const float* bias = (const float*)d_in[2];
    const float* cb   = (const float*)d_in[3];

    unsigned short* wt  = (unsigned short*)d_ws;          // 640 KB
    float* wt32         = (float*)(wt + 327680);          // 1.25 MB
    uint4* meta         = (uint4*)(wt32 + 327680);        // 5 MB
    int* idx            = (int*)(meta + 327680);          // 65,536 int
    int* hist           = idx + 65536;                    // 640 int

    float* out  = (float*)d_out;
    float* perp = out + OUT0_SIZE;

    hipLaunchKernelGGL(k_prep,   dim3(GVDIM), dim3(256), 0, stream,
                       W, wt, wt32, hist);
    hipLaunchKernelGGL(k_gemm,   dim3(1280),  dim3(256), 0, stream, hs, wt, bias, meta);
    hipLaunchKernelGGL(k_dr,     dim3(256),   dim3(256), 0, stream,
                       meta, hs, wt32, bias, idx, hist);
    hipLaunchKernelGGL(k_gather, dim3(8192),  dim3(256), 0, stream,
                       cb, idx, hist, out, perp);
}

// Round 12
// 175.299 us; speedup vs baseline: 1.0221x; 1.0221x over previous
//
#include <hip/hip_runtime.h>
#include <hip/hip_bf16.h>
#include <cmath>

#define NTOK 32768
#define HDIM 512
#define GVDIM 640
#define VDIM 320
#define DG 128
#define OUT0_SIZE (NTOK * 256)
// bf16-MFMA logit error bound: per-term 2^-9 rel, K=512 random-signed ->
// e_max ~ 0.003.  Correctness needs margin >= 2*e_max ~ 0.006; 0.010 keeps
// 1.7x headroom while halving the ambiguous (rescore) set vs 0.02.
#define MARGIN 0.010f

typedef __attribute__((ext_vector_type(8))) short s16x8;
typedef __attribute__((ext_vector_type(8))) unsigned short u16x8;
typedef __attribute__((ext_vector_type(4))) float f32x4;

__device__ __forceinline__ unsigned short f2bf(float f) {
    unsigned u = __float_as_uint(f);
    return (unsigned short)((u + 0x7FFFu + ((u >> 16) & 1u)) >> 16);  // RTNE
}

// 8x fp32 -> 8x bf16 via HW v_cvt_pk_bf16_f32 (RTNE, bit-identical to f2bf)
__device__ __forceinline__ u16x8 cvt8(const float4 a, const float4 b) {
    union { __hip_bfloat162 h[4]; u16x8 v; } u;
    u.h[0] = __float22bfloat162_rn(float2{a.x, a.y});
    u.h[1] = __float22bfloat162_rn(float2{a.z, a.w});
    u.h[2] = __float22bfloat162_rn(float2{b.x, b.y});
    u.h[3] = __float22bfloat162_rn(float2{b.z, b.w});
    return u.v;
}

// ---- prep: W [512][640] fp32 -> Wt bf16 [640][512] + Wt32 fp32 [640][512] ----
__global__ __launch_bounds__(256) void k_prep(const float* __restrict__ W,
                                              unsigned short* __restrict__ Wt,
                                              float* __restrict__ Wt32,
                                              int* __restrict__ hist,
                                              int* __restrict__ ctr) {
    int n = blockIdx.x;
    if (threadIdx.x == 0) hist[n] = 0;
    if (n == 0 && threadIdx.x == 1) ctr[0] = 0;
#pragma unroll
    for (int k2 = 0; k2 < 2; ++k2) {
        int k = k2 * 256 + threadIdx.x;
        float w = W[(size_t)k * 640 + n];
        Wt[(size_t)n * 512 + k]   = f2bf(w);
        Wt32[(size_t)n * 512 + k] = w;
    }
}

// ---- MFMA GEMM (round-4 proven): fp32 A converted in-staging via cvt_pk ----
__global__ __launch_bounds__(256) void k_gemm(
    const float* __restrict__ A32,          // [NTOK][512] fp32 (hs, raw input)
    const unsigned short* __restrict__ Bt,  // [640][512] bf16
    const float* __restrict__ bias,
    uint4* __restrict__ meta)               // [NTOK][10]
{
    __shared__ short As[128 * 64];
    __shared__ short Bs[128 * 64];

    const int tid  = threadIdx.x;
    const int lane = tid & 63;
    const int wid  = __builtin_amdgcn_readfirstlane(tid >> 6);

    // XCD-chunked swizzle, nb fastest (A re-reads are same-XCD L2/L3 hits)
    const int bid = blockIdx.x;                 // 1280 = 8 XCD * 160
    const int g   = (bid & 7) * 160 + (bid >> 3);
    const int mb  = g / 5;                      // 0..255
    const int nb  = g - mb * 5;                 // 0..4
    const int tok0 = mb * 128;
    const int col0 = nb * 128;

    const int r8 = lane >> 3;
    const int c8 = lane & 7;
    const int cl = c8 ^ r8;

    const float*          gA = A32 + (size_t)(tok0 + wid * 32 + r8) * 512 + cl * 8;
    const unsigned short* gB = Bt  + (size_t)(col0 + wid * 32 + r8) * 512 + cl * 8;
    short* wAs = As + (wid * 32 + r8) * 64 + c8 * 8;   // this thread's LDS dest

    const int quad = lane >> 4;
    const int m16  = lane & 15;
    const int wm   = (wid >> 1) * 64;
    const int wn   = (wid & 1) * 64;

    f32x4 acc[4][4];
#pragma unroll
    for (int mt = 0; mt < 4; ++mt)
#pragma unroll
        for (int nt = 0; nt < 4; ++nt) acc[mt][nt] = (f32x4){0.f, 0.f, 0.f, 0.f};

    for (int kb = 0; kb < 8; ++kb) {
        // B: async DMA into LDS (issues first; flies under the A staging work)
#pragma unroll
        for (int i = 0; i < 4; ++i) {
            __builtin_amdgcn_global_load_lds(
                (__attribute__((address_space(1))) void*)(gB + (size_t)i * 8 * 512 + kb * 64),
                (__attribute__((address_space(3))) void*)(Bs + (wid * 32 + i * 8) * 64),
                16, 0, 0);
        }
        // A: fp32 load -> HW cvt_pk bf16 -> ds_write (swizzled layout)
#pragma unroll
        for (int i = 0; i < 4; ++i) {
            const float* pa = gA + (size_t)i * 8 * 512 + kb * 64;
            float4 a0 = *(const float4*)pa;
            float4 a1 = *(const float4*)(pa + 4);
            *(u16x8*)(wAs + i * 8 * 64) = cvt8(a0, a1);
        }
        __syncthreads();
#pragma unroll
        for (int ks = 0; ks < 2; ++ks) {
            s16x8 af[4], bf[4];
            const int kch = ks * 4 + quad;
#pragma unroll
            for (int t = 0; t < 4; ++t) {
                int arow = wm + t * 16 + m16;
                af[t] = *(const s16x8*)(As + arow * 64 + (kch ^ (arow & 7)) * 8);
                int brow = wn + t * 16 + m16;
                bf[t] = *(const s16x8*)(Bs + brow * 64 + (kch ^ (brow & 7)) * 8);
            }
#pragma unroll
            for (int mt = 0; mt < 4; ++mt)
#pragma unroll
                for (int nt = 0; nt < 4; ++nt)
                    acc[mt][nt] = __builtin_amdgcn_mfma_f32_16x16x32_bf16(
                        af[mt], bf[nt], acc[mt][nt], 0, 0, 0);
        }
        __syncthreads();
    }

    float bv[4];
#pragma unroll
    for (int nt = 0; nt < 4; ++nt) bv[nt] = bias[col0 + wn + nt * 16 + m16];

    // ---- fused reduction epilogue: this wave owns chunk ch (64 cols) ----
    const int ch = (col0 + wn) >> 6;          // global chunk 0..9
#pragma unroll
    for (int mt = 0; mt < 4; ++mt) {
#pragma unroll
        for (int r = 0; r < 4; ++r) {
            float v0 = acc[mt][0][r] + bv[0];
            float v1 = acc[mt][1][r] + bv[1];
            float v2 = acc[mt][2][r] + bv[2];
            float v3 = acc[mt][3][r] + bv[3];
            float cmax = fmaxf(fmaxf(v0, v1), fmaxf(v2, v3));
#pragma unroll
            for (int off = 1; off <= 8; off <<= 1)
                cmax = fmaxf(cmax, __shfl_xor(cmax, off));   // over m16 lanes
            const float t = cmax - MARGIN;
            unsigned long long b0 = __ballot(v0 >= t);
            unsigned long long b1 = __ballot(v1 >= t);
            unsigned long long b2 = __ballot(v2 >= t);
            unsigned long long b3 = __ballot(v3 >= t);
            if (m16 == 0) {
                unsigned q16 = quad * 16;
                unsigned long long mask =
                      (((b0 >> q16) & 0xFFFFull))
                    | (((b1 >> q16) & 0xFFFFull) << 16)
                    | (((b2 >> q16) & 0xFFFFull) << 32)
                    | (((b3 >> q16) & 0xFFFFull) << 48);
                int token = tok0 + wm + mt * 16 + quad * 4 + r;
                uint4 e;
                e.x = __float_as_uint(cmax);
                e.y = (unsigned)(mask & 0xFFFFFFFFull);
                e.z = (unsigned)(mask >> 32);
                e.w = 0;
                meta[(size_t)token * 10 + ch] = e;
            }
        }
    }
}

// ---- decide: fast-path argmax from 5 chunk metas, else flag for rescore ----
__global__ __launch_bounds__(256) void k_decide(
    const uint4* __restrict__ meta, int* __restrict__ idx_out,
    int* __restrict__ hist, int* __restrict__ ctr, int* __restrict__ list)
{
    const int tg  = blockIdx.x * 256 + threadIdx.x;   // 65536
    const int tok = tg >> 1;
    const int grp = tg & 1;

    const uint4* mp = meta + (size_t)tok * 10 + grp * 5;
    float pm[5]; unsigned long long mk[5];
#pragma unroll
    for (int j = 0; j < 5; ++j) {
        uint4 e = mp[j];
        pm[j] = __uint_as_float(e.x);
        mk[j] = ((unsigned long long)e.z << 32) | e.y;
    }
    float M = fmaxf(fmaxf(fmaxf(pm[0], pm[1]), fmaxf(pm[2], pm[3])), pm[4]);
    const float thr = M - MARGIN;

    int nq = 0, qc = 0;
#pragma unroll
    for (int j = 0; j < 5; ++j)
        if (pm[j] >= thr) { ++nq; qc = j; }

    if (nq == 1 && __popcll(mk[qc]) == 1) {
        int col = qc * 64 + (__ffsll((long long)mk[qc]) - 1);
        idx_out[tg] = col;
        atomicAdd(&hist[grp * VDIM + col], 1);
    } else {
        int p = atomicAdd(ctr, 1);
        list[p] = tg;
    }
}

// ---- rescore: exact fp32 dot (coalesced via Wt32) for candidate cols ----
__global__ __launch_bounds__(256) void k_rescore(
    const uint4* __restrict__ meta, const float* __restrict__ hs,
    const float* __restrict__ Wt32, const float* __restrict__ bias,
    const int* __restrict__ list, const int* __restrict__ ctr,
    int* __restrict__ idx_out, int* __restrict__ hist)
{
    const int lane  = threadIdx.x & 63;
    const int wslot = blockIdx.x * 4 + (threadIdx.x >> 6);
    const int n = ctr[0];

    for (int it = wslot; it < n; it += 8192) {
        const int tg  = list[it];
        const int tok = tg >> 1;
        const int grp = tg & 1;

        const uint4* mp = meta + (size_t)tok * 10 + grp * 5;
        float pm[5]; unsigned long long mk[5];
#pragma unroll
        for (int j = 0; j < 5; ++j) {
            uint4 e = mp[j];
            pm[j] = __uint_as_float(e.x);
            mk[j] = ((unsigned long long)e.z << 32) | e.y;
        }
        float M = fmaxf(fmaxf(fmaxf(pm[0], pm[1]), fmaxf(pm[2], pm[3])), pm[4]);
        const float thr = M - MARGIN;

        float hsr[8];
#pragma unroll
        for (int i = 0; i < 8; ++i) hsr[i] = hs[(size_t)tok * 512 + i * 64 + lane];

        float bestv = -INFINITY;
        int   besti = 0;
#pragma unroll
        for (int j = 0; j < 5; ++j) {
            if (pm[j] < thr) continue;
            unsigned long long m = mk[j];
            while (m) {
                int b = __ffsll((long long)m) - 1; m &= m - 1;
                int col  = j * 64 + b;
                int gcol = grp * VDIM + col;
                const float* wrow = Wt32 + (size_t)gcol * 512;
                float p = 0.f;
#pragma unroll
                for (int i = 0; i < 8; ++i)
                    p = fmaf(hsr[i], wrow[i * 64 + lane], p);   // coalesced
#pragma unroll
                for (int off = 32; off >= 1; off >>= 1) p += __shfl_xor(p, off);
                float val = p + bias[gcol];
                if (val > bestv) { bestv = val; besti = col; }  // asc col => first-max
            }
        }
        if (lane == 0) {
            idx_out[tg] = besti;
            atomicAdd(&hist[grp * VDIM + besti], 1);
        }
    }
}

// ---- gather codevectors (all tokens); block 0 also computes perplexity ----
__global__ __launch_bounds__(256) void k_gather(
    const float* __restrict__ cb, const int* __restrict__ idx,
    const int* __restrict__ hist, float* __restrict__ out,
    float* __restrict__ perp)
{
    __shared__ float sh[GVDIM];
    int tid  = threadIdx.x;
    int t    = blockIdx.x * 4 + (tid >> 6);
    int lane = tid & 63;
    int g    = lane >> 5;
    int q    = lane & 31;
    int i    = idx[t * 2 + g];
    const float4* src = (const float4*)(cb + (size_t)(g * VDIM + i) * DG);
    float4 v = src[q];
    ((float4*)(out + (size_t)t * 256))[g * 32 + q] = v;

    if (blockIdx.x == 0) {
        for (int u = tid; u < GVDIM; u += 256) {
            float p = (float)hist[u] * (1.0f / (float)NTOK);
            sh[u] = p * logf(p + 1e-7f);
        }
        __syncthreads();
        if (tid == 0) {
            float s0 = 0.f, s1 = 0.f;
            for (int u = 0; u < VDIM; ++u)  s0 += sh[u];
            for (int u = VDIM; u < GVDIM; ++u) s1 += sh[u];
            perp[0] = expf(-s0) + expf(-s1);
        }
    }
}

extern "C" void kernel_launch(void* const* d_in, const int* in_sizes, int n_in,
                              void* d_out, int out_size, void* d_ws, size_t ws_size,
                              hipStream_t stream)
{
    const float* hs   = (const float*)d_in[0];
    const float* W    = (const float*)d_in[1];
    const float* bias = (const float*)d_in[2];
    const float* cb   = (const float*)d_in[3];

    unsigned short* wt  = (unsigned short*)d_ws;          // 640 KB
    float* wt32         = (float*)(wt + 327680);          // 1.25 MB
    uint4* meta         = (uint4*)(wt32 + 327680);        // 5 MB
    int* idx            = (int*)(meta + 327680);          // 65,536 int
    int* hist           = idx + 65536;                    // 640 int
    int* ctr            = hist + GVDIM;                   // 1 int (+1 pad)
    int* list           = ctr + 2;                        // up to 65,536 int

    float* out  = (float*)d_out;
    float* perp = out + OUT0_SIZE;

    hipLaunchKernelGGL(k_prep,    dim3(GVDIM), dim3(256), 0, stream,
                       W, wt, wt32, hist, ctr);
    hipLaunchKernelGGL(k_gemm,    dim3(1280),  dim3(256), 0, stream, hs, wt, bias, meta);
    hipLaunchKernelGGL(k_decide,  dim3(256),   dim3(256), 0, stream,
                       meta, idx, hist, ctr, list);
    hipLaunchKernelGGL(k_rescore, dim3(2048),  dim3(256), 0, stream,
                       meta, hs, wt32, bias, list, ctr, idx, hist);
    hipLaunchKernelGGL(k_gather,  dim3(8192),  dim3(256), 0, stream,
                       cb, idx, hist, out, perp);
}